// Round 12
// baseline (81.723 us; speedup 1.0000x reference)
//
#include <hip/hip_runtime.h>
#include <math.h>

#define BB 64
#define CC 128
#define KK 64
#define NN 4096
#define PCH 128            // pixels per chunk
#define NCH 4              // chunks per block
#define SLAB (PCH*NCH)     // 512 pixels per block
#define NSLAB (NN/SLAB)    // 8 slabs
#define VSTRIDE ((size_t)BB*KK*CC)   // one vlad partial copy (524288 floats)

typedef __attribute__((ext_vector_type(8))) short short8;
typedef __attribute__((ext_vector_type(16))) float f32x16;

// fp32 -> bf16 bits, round-to-nearest-even
__device__ __forceinline__ unsigned f2bf(float f) {
    unsigned u = __float_as_uint(f);
    return (u + 0x7fffu + ((u >> 16) & 1u)) >> 16;
}

__device__ __forceinline__ short8 pack8(float4 a, float4 b) {
    short8 r;
    r[0]=(short)f2bf(a.x); r[1]=(short)f2bf(a.y); r[2]=(short)f2bf(a.z); r[3]=(short)f2bf(a.w);
    r[4]=(short)f2bf(b.x); r[5]=(short)f2bf(b.y); r[6]=(short)f2bf(b.z); r[7]=(short)f2bf(b.w);
    return r;
}

// LDS-only fence barrier: drains ds ops for cross-wave visibility but leaves
// global loads (vmcnt) in flight across the barrier (prefetch survives).
#define LDS_FENCE_BARRIER() do {                                  \
    asm volatile("s_waitcnt lgkmcnt(0)" ::: "memory");            \
    __builtin_amdgcn_s_barrier();                                 \
} while (0)

// ---------------- Phase 1: logits -> softmax -> vlad partials (MFMA bf16) ----
// MFMA 32x32x16 layouts (verified round 2, absmax 1.2e-4 PASS):
//   A[m][k]: lane m=l&31, k=8*(l>>5)+j ; B[k][n]: lane n=l&31, k=8*(l>>5)+j
//   C/D: col=l&31, row=(r&3)+8*(r>>2)+4*(l>>5)
// LDS 16B-chunk XOR swizzle: chunk' = chunk ^ (row & 7)
// Scoreboard lessons baked in:
//   - r2/r8/r9: 128-reg cap spills this kernel -> need 256-reg budget.
//   - r2/r10: F reading x from global regresses 2x -> both operands from LDS.
//   - r7 (48.9us): cross-chunk RAW prefetch works, 1 barrier domain limits it.
//   - r11 (60.4us): 2x256-thr barrier domains work, no prefetch limits it.
//   - THIS ROUND: both. (256,2) = 256-reg cap, 2 blocks/CU (LDS 65KB each),
//     pf[16] raw prefetch crossing the vmcnt-preserving fences.
__global__ __launch_bounds__(256, 2) void nv_phase1(
    const float* __restrict__ x,      // [B][C][N]
    const float* __restrict__ convw,  // [K][C]
    float* __restrict__ vlad,         // [B][K][C]  slab-0 partial (d_out)
    float* __restrict__ wsf)          // slabs 1..7 vlad partials + 8 asum partials
{
    __shared__ alignas(16) unsigned short xs[PCH*CC];  // 32 KB bf16 x, [n][c], swizzled
    __shared__ alignas(16) unsigned short xc[CC*PCH];  // 32 KB bf16 x, [c][n], swizzled

    unsigned short* al = xs;   // a[k][n] bf16 [64][128] = 16 KB aliases xs rows 0..63:
                               // xs dead after C (barrier #2); al dead before next A.

    const int t  = threadIdx.x;
    const int b  = blockIdx.y;
    const int slab = blockIdx.x;
    const int n_slab = slab * SLAB;
    const int l   = t & 63;
    const int wid = t >> 6;           // wave 0..3
    const int ln  = l & 31;
    const int q   = l >> 5;
    const int r4  = t & 3;

    const float* xb = x + (size_t)b * CC * NN;
    const int n_ = ln + 32*wid;       // this wave's pixel (chunk-local, 0..127)
    const int c2 = ln + 32*wid;       // F: A row (channel), c-tile = wid

    // ---- prologue: chunk-0 staging loads held RAW (converted in A) ----
    float4 pf[16];
#pragma unroll
    for (int i = 0; i < 16; ++i) {
        int u = (t >> 2) + 64 * i, cQ = u >> 5, nQ = u & 31;
        pf[i] = *(const float4*)(xb + (size_t)(4*cQ + r4) * NN + n_slab + 4*nQ);
    }

    // ---- preload conv_w fragments for BOTH k-tiles (reused all chunks) ----
    short8 wfrag0[8], wfrag1[8];
    {
        const float* wr0 = convw + (size_t)ln * CC + 8*q;
        const float* wr1 = convw + (size_t)(ln + 32) * CC + 8*q;
#pragma unroll
        for (int cs = 0; cs < 8; ++cs) {
            wfrag0[cs] = pack8(*(const float4*)(wr0 + 16*cs), *(const float4*)(wr0 + 16*cs + 4));
            wfrag1[cs] = pack8(*(const float4*)(wr1 + 16*cs), *(const float4*)(wr1 + 16*cs + 4));
        }
    }

    f32x16 vacc0, vacc1;
#pragma unroll
    for (int i = 0; i < 16; ++i) { vacc0[i] = 0.f; vacc1[i] = 0.f; }
    float asacc0 = 0.f, asacc1 = 0.f;

#pragma unroll 1
    for (int chk = 0; chk < NCH; ++chk) {
        // ---- A: convert pf -> bf16, write xs[n][c] + xc[c][n] ----
#pragma unroll
        for (int i = 0; i < 16; ++i) {
            int u = (t >> 2) + 64 * i, cQ = u >> 5, nQ = u & 31;
            unsigned d0 = f2bf(pf[i].x) | (f2bf(pf[i].y) << 16);
            unsigned d1 = f2bf(pf[i].z) | (f2bf(pf[i].w) << 16);
            // xc: straight write, 4 consecutive n at row c
            int c = 4*cQ + r4;
            *(uint2*)((char*)xc + c*256 + ((((nQ >> 1) ^ (c & 7)) << 4) | ((nQ & 1) * 8)))
                = make_uint2(d0, d1);
            // xs: quad 4x4 shuffle transpose (verified round 2)
            unsigned q0 = (unsigned)__shfl_xor((int)d0, 1);
            unsigned q1 = (unsigned)__shfl_xor((int)d1, 1);
            unsigned e, f;
            if (r4 & 1) { e = (q0 >> 16) | (d0 & 0xffff0000u);
                          f = (q1 >> 16) | (d1 & 0xffff0000u); }
            else        { e = (d0 & 0xffffu) | (q0 << 16);
                          f = (d1 & 0xffffu) | (q1 << 16); }
            unsigned s2 = (unsigned)__shfl_xor((int)((r4 & 2) ? e : f), 2);
            unsigned w0 = (r4 & 2) ? s2 : e;
            unsigned w1 = (r4 & 2) ? f : s2;
            int nn  = 4*nQ + r4;
            int chp = (cQ >> 1) ^ (nn & 7);
            *(uint2*)((char*)xs + nn*256 + (chp << 4) + (cQ & 1)*8) = make_uint2(w0, w1);
        }
        // ---- B: issue next chunk's staging loads (hidden under C/D/E/F) ----
        if (chk + 1 < NCH) {
            const int gn1 = n_slab + (chk + 1) * PCH;
#pragma unroll
            for (int i = 0; i < 16; ++i) {
                int u = (t >> 2) + 64 * i, cQ = u >> 5, nQ = u & 31;
                pf[i] = *(const float4*)(xb + (size_t)(4*cQ + r4) * NN + gn1 + 4*nQ);
            }
        }
        LDS_FENCE_BARRIER();   // #1: xs, xc visible

        // ---- C: logits, BOTH k-tiles for this wave's 32 pixels ----
        f32x16 lacc0, lacc1;
#pragma unroll
        for (int i = 0; i < 16; ++i) { lacc0[i] = 0.f; lacc1[i] = 0.f; }
#pragma unroll
        for (int cs = 0; cs < 8; ++cs) {
            int chx = (2*cs + q) ^ (n_ & 7);
            short8 xf = *(const short8*)((const char*)xs + n_*256 + (chx << 4));
            lacc0 = __builtin_amdgcn_mfma_f32_32x32x16_bf16(wfrag0[cs], xf, lacc0, 0, 0, 0);
            lacc1 = __builtin_amdgcn_mfma_f32_32x32x16_bf16(wfrag1[cs], xf, lacc1, 0, 0, 0);
        }

        // ---- D: softmax over all 64 k, register-local (no LDS roundtrip) ----
        float ssum = 0.f;
#pragma unroll
        for (int i = 0; i < 16; ++i) { float e2 = __expf(lacc0[i]); lacc0[i] = e2; ssum += e2; }
#pragma unroll
        for (int i = 0; i < 16; ++i) { float e2 = __expf(lacc1[i]); lacc1[i] = e2; ssum += e2; }
        ssum += __shfl_xor(ssum, 32);   // q-halves hold complementary k rows
        float inv = 1.0f / ssum;
        LDS_FENCE_BARRIER();   // #2: all xs reads done (al aliases xs)

        // ---- E: a -> al[k][n_], 32 scalar b16 writes, swizzle ^ (k&7) ----
#pragma unroll
        for (int i = 0; i < 16; ++i) {
            float a = lacc0[i] * inv;
            int k_ = 4*q + (i & 3) + 8*(i >> 2);
            al[k_*128 + ((((n_ >> 3) ^ (k_ & 7)) << 3) | (n_ & 7))] = (unsigned short)f2bf(a);
        }
#pragma unroll
        for (int i = 0; i < 16; ++i) {
            float a = lacc1[i] * inv;
            int k_ = 32 + 4*q + (i & 3) + 8*(i >> 2);
            al[k_*128 + ((((n_ >> 3) ^ (k_ & 7)) << 3) | (n_ & 7))] = (unsigned short)f2bf(a);
        }
        LDS_FENCE_BARRIER();   // #3: al ready

        // ---- F: vlad, BOTH k-tiles for this wave's c-tile; all from LDS ----
#pragma unroll
        for (int ns = 0; ns < 8; ++ns) {
            int ca = (2*ns + q) ^ (c2 & 7);
            short8 af = *(const short8*)((const char*)xc + c2*256 + (ca << 4));
            int cb = (2*ns + q) ^ (ln & 7);    // (ln+32)&7 == ln&7
            short8 bf0 = *(const short8*)((const char*)al + ln*256        + (cb << 4));
            short8 bf1 = *(const short8*)((const char*)al + (ln + 32)*256 + (cb << 4));
            vacc0 = __builtin_amdgcn_mfma_f32_32x32x16_bf16(af, bf0, vacc0, 0, 0, 0);
            vacc1 = __builtin_amdgcn_mfma_f32_32x32x16_bf16(af, bf1, vacc1, 0, 0, 0);
            if (wid == 0) {   // asum: all waves read identical al rows; one counts
#pragma unroll
                for (int e = 0; e < 8; ++e) {
                    asacc0 += __uint_as_float(((unsigned)(unsigned short)bf0[e]) << 16);
                    asacc1 += __uint_as_float(((unsigned)(unsigned short)bf1[e]) << 16);
                }
            }
        }
        LDS_FENCE_BARRIER();   // #4: al/xc reads done; LDS free for next A
    }

    // ---- epilogue: vlad partial tile -> plain float4 stores (NO atomics) ----
    {
        float* base = (slab == 0)
            ? vlad + (size_t)b * KK * CC
            : wsf + (size_t)(slab - 1) * VSTRIDE + (size_t)b * KK * CC;
        float* vb0 = base + (size_t)ln * CC        + 32*wid + 4*q;
        float* vb1 = base + (size_t)(ln + 32) * CC + 32*wid + 4*q;
#pragma unroll
        for (int g = 0; g < 4; ++g) {
            float4 o0, o1;
            o0.x = vacc0[4*g+0]; o0.y = vacc0[4*g+1]; o0.z = vacc0[4*g+2]; o0.w = vacc0[4*g+3];
            o1.x = vacc1[4*g+0]; o1.y = vacc1[4*g+1]; o1.z = vacc1[4*g+2]; o1.w = vacc1[4*g+3];
            *(float4*)(vb0 + 8*g) = o0;
            *(float4*)(vb1 + 8*g) = o1;
        }
    }

    // ---- asum: combine q-halves in wave 0, plain stores ----
    if (wid == 0) {
        asacc0 += __shfl_xor(asacc0, 32);
        asacc1 += __shfl_xor(asacc1, 32);
        if (q == 0) {
            float* ab = wsf + 7 * VSTRIDE + (size_t)slab * BB * KK + (size_t)b * KK;
            ab[ln]      = asacc0;
            ab[ln + 32] = asacc1;
        }
    }
}

// ------- Phase 2: sum 8 partials + centroid subtract + intra/global L2 -------
// 512 threads (8 waves x 8 rows): halves the serial per-thread chain vs 256.
__global__ __launch_bounds__(512) void nv_phase2(
    float* __restrict__ vlad,        // [B][K][C] in: slab-0 partial / out: result
    const float* __restrict__ wsf,   // slabs 1..7 vlad partials + 8 asum partials
    const float* __restrict__ cent)  // [K][C]
{
    __shared__ float gred[8];
    const int b    = blockIdx.x;
    const int w    = threadIdx.x >> 6;   // wave 0..7 -> 8 rows each
    const int lane = threadIdx.x & 63;
    const float* ap = wsf + 7 * VSTRIDE; // [8][B][K]

    float v[16];
    float gsum = 0.f;
#pragma unroll
    for (int r = 0; r < 8; r++) {
        int k = w * 8 + r;
        float a = 0.f;
#pragma unroll
        for (int s = 0; s < NSLAB; ++s) a += ap[(size_t)s * BB * KK + b * KK + k];
        size_t o = ((size_t)b * KK + k) * CC + lane;
        float x0 = vlad[o], x1 = vlad[o + 64];
#pragma unroll
        for (int s = 0; s < NSLAB - 1; ++s) {
            x0 += wsf[(size_t)s * VSTRIDE + o];
            x1 += wsf[(size_t)s * VSTRIDE + o + 64];
        }
        x0 -= a * cent[k * CC + lane];
        x1 -= a * cent[k * CC + lane + 64];
        float ss = x0 * x0 + x1 * x1;
#pragma unroll
        for (int m = 1; m < 64; m <<= 1) ss += __shfl_xor(ss, m, 64);
        float rn = 1.0f / fmaxf(sqrtf(ss), 1e-12f);
        v[2 * r]     = x0 * rn;
        v[2 * r + 1] = x1 * rn;
        gsum += ss * rn * rn;
    }
    if (lane == 0) gred[w] = gsum;
    __syncthreads();
    float g = gred[0] + gred[1] + gred[2] + gred[3]
            + gred[4] + gred[5] + gred[6] + gred[7];
    float gs = 1.0f / fmaxf(sqrtf(g), 1e-12f);
#pragma unroll
    for (int r = 0; r < 8; r++) {
        int k = w * 8 + r;
        vlad[((size_t)b * KK + k) * CC + lane]      = v[2 * r]     * gs;
        vlad[((size_t)b * KK + k) * CC + lane + 64] = v[2 * r + 1] * gs;
    }
}

extern "C" void kernel_launch(void* const* d_in, const int* in_sizes, int n_in,
                              void* d_out, int out_size, void* d_ws, size_t ws_size,
                              hipStream_t stream) {
    const float* x     = (const float*)d_in[0];
    const float* convw = (const float*)d_in[1];
    const float* cent  = (const float*)d_in[2];
    float* out = (float*)d_out;
    float* wsf = (float*)d_ws;   // 7*VSTRIDE vlad partials + 8*B*K asum = ~14.8 MB

    nv_phase1<<<dim3(NSLAB, BB), 256, 0, stream>>>(x, convw, out, wsf);
    nv_phase2<<<BB, 512, 0, stream>>>(out, wsf, cent);
}

// Round 13
// 74.700 us; speedup vs baseline: 1.0940x; 1.0940x over previous
//
#include <hip/hip_runtime.h>
#include <math.h>

#define BB 64
#define CC 128
#define KK 64
#define NN 4096
#define PCH 128            // pixels per chunk
#define NCH 4              // chunks per block
#define SLAB (PCH*NCH)     // 512 pixels per block
#define NSLAB (NN/SLAB)    // 8 slabs
#define VSTRIDE ((size_t)BB*KK*CC)   // one vlad partial copy (524288 floats)

typedef __attribute__((ext_vector_type(8))) short short8;
typedef __attribute__((ext_vector_type(16))) float f32x16;

// fp32 -> bf16 bits, round-to-nearest-even
__device__ __forceinline__ unsigned f2bf(float f) {
    unsigned u = __float_as_uint(f);
    return (u + 0x7fffu + ((u >> 16) & 1u)) >> 16;
}

__device__ __forceinline__ short8 pack8(float4 a, float4 b) {
    short8 r;
    r[0]=(short)f2bf(a.x); r[1]=(short)f2bf(a.y); r[2]=(short)f2bf(a.z); r[3]=(short)f2bf(a.w);
    r[4]=(short)f2bf(b.x); r[5]=(short)f2bf(b.y); r[6]=(short)f2bf(b.z); r[7]=(short)f2bf(b.w);
    return r;
}

// LDS-only fence barrier: drains ds ops for cross-wave visibility but leaves
// global loads (vmcnt) in flight across the barrier (prefetch survives).
#define LDS_FENCE_BARRIER() do {                                  \
    asm volatile("s_waitcnt lgkmcnt(0)" ::: "memory");            \
    __builtin_amdgcn_s_barrier();                                 \
} while (0)

// ---------------- Phase 1: logits -> softmax -> vlad partials (MFMA bf16) ----
// MFMA 32x32x16 layouts (verified round 2, absmax 1.2e-4 PASS):
//   A[m][k]: lane m=l&31, k=8*(l>>5)+j ; B[k][n]: lane n=l&31, k=8*(l>>5)+j
//   C/D: col=l&31, row=(r&3)+8*(r>>2)+4*(l>>5)
// LDS 16B-chunk XOR swizzle: chunk' = chunk ^ (row & 7)
// Register ledger (the decider in r2/r8/r9/r12 — all spilled, all lost):
//   with 64 AGPRs live the allocator caps arch VGPRs ~128. Persistent here:
//   pf[16]=64 + ONE wfrag set=16 + addr ~10 + temps ~20 = ~110 <= 128. The
//   r12 spill was the second wfrag set (+32). Softmax k-reduction therefore
//   goes back to the r7-proven redsm roundtrip -- structurally FREE because
//   barrier #2 (al aliases xs) exists anyway.
// Structure: 2x256-thread blocks/CU (two independent barrier domains, r11)
//   + raw cross-chunk prefetch over vmcnt-preserving fences (r7).
__global__ __launch_bounds__(256, 2) void nv_phase1(
    const float* __restrict__ x,      // [B][C][N]
    const float* __restrict__ convw,  // [K][C]
    float* __restrict__ vlad,         // [B][K][C]  slab-0 partial (d_out)
    float* __restrict__ wsf)          // slabs 1..7 vlad partials + 8 asum partials
{
    __shared__ alignas(16) unsigned short xs[PCH*CC];  // 32 KB bf16 x, [n][c], swizzled
    __shared__ alignas(16) unsigned short xc[CC*PCH];  // 32 KB bf16 x, [c][n], swizzled
    __shared__ float redsm[2][PCH];                    // softmax denom cross-wave (1 KB)

    unsigned short* al = xs;   // a[k][n] bf16 [64][128] = 16 KB aliases xs rows 0..63:
                               // xs dead after C (barrier #2); al dead before next A.

    const int t  = threadIdx.x;
    const int b  = blockIdx.y;
    const int slab = blockIdx.x;
    const int n_slab = slab * SLAB;
    const int l   = t & 63;
    const int wid = t >> 6;           // wave 0..3
    const int ln  = l & 31;
    const int q   = l >> 5;
    const int r4  = t & 3;
    const int kt  = wid & 1;          // logits k-tile (0..1)
    const int nt2 = wid >> 1;         // logits pixel-half (0..1)

    const float* xb = x + (size_t)b * CC * NN;
    const int pa = ln + 64*nt2;       // logits pixel group a (chunk-local)
    const int pb = pa + 32;           // logits pixel group b
    const int c2 = ln + 32*wid;       // F: A row (channel), c-tile = wid

    // ---- prologue: chunk-0 staging loads held RAW (converted in A) ----
    float4 pf[16];
#pragma unroll
    for (int i = 0; i < 16; ++i) {
        int u = (t >> 2) + 64 * i, cQ = u >> 5, nQ = u & 31;
        pf[i] = *(const float4*)(xb + (size_t)(4*cQ + r4) * NN + n_slab + 4*nQ);
    }

    // ---- preload conv_w fragments, ONE k-tile per wave (16 regs) ----
    short8 wfrag[8];
    {
        const float* wr = convw + (size_t)(ln + 32*kt) * CC + 8*q;
#pragma unroll
        for (int cs = 0; cs < 8; ++cs)
            wfrag[cs] = pack8(*(const float4*)(wr + 16*cs), *(const float4*)(wr + 16*cs + 4));
    }

    f32x16 vacc0, vacc1;
#pragma unroll
    for (int i = 0; i < 16; ++i) { vacc0[i] = 0.f; vacc1[i] = 0.f; }
    float asacc0 = 0.f, asacc1 = 0.f;

#pragma unroll 1
    for (int chk = 0; chk < NCH; ++chk) {
        // ---- A: convert pf -> bf16, write xs[n][c] + xc[c][n] ----
#pragma unroll
        for (int i = 0; i < 16; ++i) {
            int u = (t >> 2) + 64 * i, cQ = u >> 5, nQ = u & 31;
            unsigned d0 = f2bf(pf[i].x) | (f2bf(pf[i].y) << 16);
            unsigned d1 = f2bf(pf[i].z) | (f2bf(pf[i].w) << 16);
            // xc: straight write, 4 consecutive n at row c
            int c = 4*cQ + r4;
            *(uint2*)((char*)xc + c*256 + ((((nQ >> 1) ^ (c & 7)) << 4) | ((nQ & 1) * 8)))
                = make_uint2(d0, d1);
            // xs: quad 4x4 shuffle transpose (verified round 2)
            unsigned q0 = (unsigned)__shfl_xor((int)d0, 1);
            unsigned q1 = (unsigned)__shfl_xor((int)d1, 1);
            unsigned e, f;
            if (r4 & 1) { e = (q0 >> 16) | (d0 & 0xffff0000u);
                          f = (q1 >> 16) | (d1 & 0xffff0000u); }
            else        { e = (d0 & 0xffffu) | (q0 << 16);
                          f = (d1 & 0xffffu) | (q1 << 16); }
            unsigned s2 = (unsigned)__shfl_xor((int)((r4 & 2) ? e : f), 2);
            unsigned w0 = (r4 & 2) ? s2 : e;
            unsigned w1 = (r4 & 2) ? f : s2;
            int nn  = 4*nQ + r4;
            int chp = (cQ >> 1) ^ (nn & 7);
            *(uint2*)((char*)xs + nn*256 + (chp << 4) + (cQ & 1)*8) = make_uint2(w0, w1);
        }
        // ---- B: issue next chunk's staging loads (hidden under C/D/E/F) ----
        if (chk + 1 < NCH) {
            const int gn1 = n_slab + (chk + 1) * PCH;
#pragma unroll
            for (int i = 0; i < 16; ++i) {
                int u = (t >> 2) + 64 * i, cQ = u >> 5, nQ = u & 31;
                pf[i] = *(const float4*)(xb + (size_t)(4*cQ + r4) * NN + gn1 + 4*nQ);
            }
        }
        LDS_FENCE_BARRIER();   // #1: xs, xc visible

        // ---- C: logits, k-tile kt, pixel groups pa/pb (64 px per wave) ----
        f32x16 lacc_a, lacc_b;
#pragma unroll
        for (int i = 0; i < 16; ++i) { lacc_a[i] = 0.f; lacc_b[i] = 0.f; }
#pragma unroll
        for (int cs = 0; cs < 8; ++cs) {
            int chx = (2*cs + q) ^ (ln & 7);   // pa&7 == pb&7 == ln&7
            short8 xfa = *(const short8*)((const char*)xs + pa*256 + (chx << 4));
            short8 xfb = *(const short8*)((const char*)xs + pb*256 + (chx << 4));
            lacc_a = __builtin_amdgcn_mfma_f32_32x32x16_bf16(wfrag[cs], xfa, lacc_a, 0, 0, 0);
            lacc_b = __builtin_amdgcn_mfma_f32_32x32x16_bf16(wfrag[cs], xfb, lacc_b, 0, 0, 0);
        }

        // ---- D: exp + per-k-tile sums; cross-k-tile via redsm (free: bar #2) ----
        float ssa = 0.f, ssb = 0.f;
#pragma unroll
        for (int i = 0; i < 16; ++i) { float e2 = __expf(lacc_a[i]); lacc_a[i] = e2; ssa += e2; }
#pragma unroll
        for (int i = 0; i < 16; ++i) { float e2 = __expf(lacc_b[i]); lacc_b[i] = e2; ssb += e2; }
        ssa += __shfl_xor(ssa, 32);   // q-halves hold complementary k rows of tile kt
        ssb += __shfl_xor(ssb, 32);
        if (q == 0) { redsm[kt][pa] = ssa; redsm[kt][pb] = ssb; }
        LDS_FENCE_BARRIER();   // #2: xs reads done (al aliases xs) + redsm visible

        // ---- E: scale, a -> al[k][n], swizzled scalar b16 writes ----
        float inva = 1.0f / (redsm[0][pa] + redsm[1][pa]);
        float invb = 1.0f / (redsm[0][pb] + redsm[1][pb]);
#pragma unroll
        for (int i = 0; i < 16; ++i) {
            int k_ = 32*kt + 4*q + (i & 3) + 8*(i >> 2);
            al[k_*128 + ((((pa >> 3) ^ (k_ & 7)) << 3) | (pa & 7))]
                = (unsigned short)f2bf(lacc_a[i] * inva);
            al[k_*128 + ((((pb >> 3) ^ (k_ & 7)) << 3) | (pb & 7))]
                = (unsigned short)f2bf(lacc_b[i] * invb);
        }
        LDS_FENCE_BARRIER();   // #3: al ready

        // ---- F: vlad, BOTH k-tiles for this wave's c-tile; all from LDS ----
#pragma unroll
        for (int ns = 0; ns < 8; ++ns) {
            int ca = (2*ns + q) ^ (c2 & 7);
            short8 af = *(const short8*)((const char*)xc + c2*256 + (ca << 4));
            int cb = (2*ns + q) ^ (ln & 7);    // (ln+32)&7 == ln&7
            short8 bf0 = *(const short8*)((const char*)al + ln*256        + (cb << 4));
            short8 bf1 = *(const short8*)((const char*)al + (ln + 32)*256 + (cb << 4));
            vacc0 = __builtin_amdgcn_mfma_f32_32x32x16_bf16(af, bf0, vacc0, 0, 0, 0);
            vacc1 = __builtin_amdgcn_mfma_f32_32x32x16_bf16(af, bf1, vacc1, 0, 0, 0);
            if (wid == 0) {   // asum: all waves read identical al rows; one counts
#pragma unroll
                for (int e = 0; e < 8; ++e) {
                    asacc0 += __uint_as_float(((unsigned)(unsigned short)bf0[e]) << 16);
                    asacc1 += __uint_as_float(((unsigned)(unsigned short)bf1[e]) << 16);
                }
            }
        }
        LDS_FENCE_BARRIER();   // #4: al/xc reads done; LDS free for next A
    }

    // ---- epilogue: vlad partial tile -> plain float4 stores (NO atomics) ----
    {
        float* base = (slab == 0)
            ? vlad + (size_t)b * KK * CC
            : wsf + (size_t)(slab - 1) * VSTRIDE + (size_t)b * KK * CC;
        float* vb0 = base + (size_t)ln * CC        + 32*wid + 4*q;
        float* vb1 = base + (size_t)(ln + 32) * CC + 32*wid + 4*q;
#pragma unroll
        for (int g = 0; g < 4; ++g) {
            float4 o0, o1;
            o0.x = vacc0[4*g+0]; o0.y = vacc0[4*g+1]; o0.z = vacc0[4*g+2]; o0.w = vacc0[4*g+3];
            o1.x = vacc1[4*g+0]; o1.y = vacc1[4*g+1]; o1.z = vacc1[4*g+2]; o1.w = vacc1[4*g+3];
            *(float4*)(vb0 + 8*g) = o0;
            *(float4*)(vb1 + 8*g) = o1;
        }
    }

    // ---- asum: combine q-halves in wave 0, plain stores ----
    if (wid == 0) {
        asacc0 += __shfl_xor(asacc0, 32);
        asacc1 += __shfl_xor(asacc1, 32);
        if (q == 0) {
            float* ab = wsf + 7 * VSTRIDE + (size_t)slab * BB * KK + (size_t)b * KK;
            ab[ln]      = asacc0;
            ab[ln + 32] = asacc1;
        }
    }
}

// ------- Phase 2: sum 8 partials + centroid subtract + intra/global L2 -------
// 512 threads (8 waves x 8 rows): halves the serial per-thread chain vs 256.
__global__ __launch_bounds__(512) void nv_phase2(
    float* __restrict__ vlad,        // [B][K][C] in: slab-0 partial / out: result
    const float* __restrict__ wsf,   // slabs 1..7 vlad partials + 8 asum partials
    const float* __restrict__ cent)  // [K][C]
{
    __shared__ float gred[8];
    const int b    = blockIdx.x;
    const int w    = threadIdx.x >> 6;   // wave 0..7 -> 8 rows each
    const int lane = threadIdx.x & 63;
    const float* ap = wsf + 7 * VSTRIDE; // [8][B][K]

    float v[16];
    float gsum = 0.f;
#pragma unroll
    for (int r = 0; r < 8; r++) {
        int k = w * 8 + r;
        float a = 0.f;
#pragma unroll
        for (int s = 0; s < NSLAB; ++s) a += ap[(size_t)s * BB * KK + b * KK + k];
        size_t o = ((size_t)b * KK + k) * CC + lane;
        float x0 = vlad[o], x1 = vlad[o + 64];
#pragma unroll
        for (int s = 0; s < NSLAB - 1; ++s) {
            x0 += wsf[(size_t)s * VSTRIDE + o];
            x1 += wsf[(size_t)s * VSTRIDE + o + 64];
        }
        x0 -= a * cent[k * CC + lane];
        x1 -= a * cent[k * CC + lane + 64];
        float ss = x0 * x0 + x1 * x1;
#pragma unroll
        for (int m = 1; m < 64; m <<= 1) ss += __shfl_xor(ss, m, 64);
        float rn = 1.0f / fmaxf(sqrtf(ss), 1e-12f);
        v[2 * r]     = x0 * rn;
        v[2 * r + 1] = x1 * rn;
        gsum += ss * rn * rn;
    }
    if (lane == 0) gred[w] = gsum;
    __syncthreads();
    float g = gred[0] + gred[1] + gred[2] + gred[3]
            + gred[4] + gred[5] + gred[6] + gred[7];
    float gs = 1.0f / fmaxf(sqrtf(g), 1e-12f);
#pragma unroll
    for (int r = 0; r < 8; r++) {
        int k = w * 8 + r;
        vlad[((size_t)b * KK + k) * CC + lane]      = v[2 * r]     * gs;
        vlad[((size_t)b * KK + k) * CC + lane + 64] = v[2 * r + 1] * gs;
    }
}

extern "C" void kernel_launch(void* const* d_in, const int* in_sizes, int n_in,
                              void* d_out, int out_size, void* d_ws, size_t ws_size,
                              hipStream_t stream) {
    const float* x     = (const float*)d_in[0];
    const float* convw = (const float*)d_in[1];
    const float* cent  = (const float*)d_in[2];
    float* out = (float*)d_out;
    float* wsf = (float*)d_ws;   // 7*VSTRIDE vlad partials + 8*B*K asum = ~14.8 MB

    nv_phase1<<<dim3(NSLAB, BB), 256, 0, stream>>>(x, convw, out, wsf);
    nv_phase2<<<BB, 512, 0, stream>>>(out, wsf, cent);
}

// Round 14
// 74.171 us; speedup vs baseline: 1.1018x; 1.0071x over previous
//
#include <hip/hip_runtime.h>
#include <math.h>

#define BB 64
#define CC 128
#define KK 64
#define NN 4096
#define PCH 256            // pixels per chunk (r14: doubled to halve fence count)
#define NCH 4              // chunks per block
#define SLAB (PCH*NCH)     // 1024 pixels per block
#define NSLAB (NN/SLAB)    // 4 slabs
#define VSTRIDE ((size_t)BB*KK*CC)   // one vlad partial copy (524288 floats)

typedef __attribute__((ext_vector_type(8))) short short8;
typedef __attribute__((ext_vector_type(16))) float f32x16;

// fp32 -> bf16 bits, round-to-nearest-even
__device__ __forceinline__ unsigned f2bf(float f) {
    unsigned u = __float_as_uint(f);
    return (u + 0x7fffu + ((u >> 16) & 1u)) >> 16;
}

__device__ __forceinline__ short8 pack8(float4 a, float4 b) {
    short8 r;
    r[0]=(short)f2bf(a.x); r[1]=(short)f2bf(a.y); r[2]=(short)f2bf(a.z); r[3]=(short)f2bf(a.w);
    r[4]=(short)f2bf(b.x); r[5]=(short)f2bf(b.y); r[6]=(short)f2bf(b.z); r[7]=(short)f2bf(b.w);
    return r;
}

// LDS-only fence barrier: drains ds ops for cross-wave visibility but leaves
// global loads (vmcnt) in flight across the barrier (prefetch survives).
#define LDS_FENCE_BARRIER() do {                                  \
    asm volatile("s_waitcnt lgkmcnt(0)" ::: "memory");            \
    __builtin_amdgcn_s_barrier();                                 \
} while (0)

// ---------------- Phase 1: logits -> softmax -> vlad partials (MFMA bf16) ----
// MFMA 32x32x16 layouts (verified round 2):
//   A[m][k]: lane m=l&31, k=8*(l>>5)+j ; B[k][n]: lane n=l&31, k=8*(l>>5)+j
//   C/D: col=l&31, row=(r&3)+8*(r>>2)+4*(l>>5)
// Ledger verdict (r8/r9/r12/r13 all spilled at the 128-reg cap): prefetch
// structure lives ONLY at (512,2)'s 256-reg budget -> 1 block/CU. Therefore
// attack the barrier convoy instead: PCH=256 halves fences to 16 convoys,
// each amortizing 2x work. LDS 130KB (xs 64 + xc 64 + redsm; al aliases xs)
// is free at 1 block/CU. All addressing verbatim from passing rounds
// (r10 staging/al 512B rows, r8/r9 F/epilogue/asum, r13 C/D softmax).
__global__ __launch_bounds__(512, 2) void nv_phase1(
    const float* __restrict__ x,      // [B][C][N]
    const float* __restrict__ convw,  // [K][C]
    float* __restrict__ vlad,         // [B][K][C]  slab-0 partial (d_out)
    float* __restrict__ wsf)          // slabs 1..3 vlad partials + 4 asum partials
{
    __shared__ alignas(16) unsigned short xs[PCH*CC];  // 64 KB bf16 x, [n][c], swizzled
    __shared__ alignas(16) unsigned short xc[CC*PCH];  // 64 KB bf16 x, [c][n], swizzled
    __shared__ float redsm[2][PCH];                    // softmax denom cross-wave (2 KB)

    unsigned short* al = xs;   // a[k][n] bf16 [64][256] = 32 KB aliases xs bytes 0..32K:
                               // xs dead after C (barrier #2); al dead before next A.

    const int t  = threadIdx.x;
    const int b  = blockIdx.y;
    const int slab = blockIdx.x;
    const int n_slab = slab * SLAB;
    const int l   = t & 63;
    const int wid = t >> 6;           // wave 0..7
    const int ln  = l & 31;
    const int q   = l >> 5;
    const int r4  = t & 3;
    const int kt  = wid & 1;          // C: k-tile (0..1)
    const int nt  = wid >> 1;         // C: n-tile pair (0..3)
    const int ct  = wid & 3;          // F: c-tile (0..3)
    const int kt2 = wid >> 2;         // F: k-tile (0..1)

    const float* xb = x + (size_t)b * CC * NN;
    const int pa = ln + 64*nt;        // C/E pixel group a (chunk-local 0..255)
    const int pb = pa + 32;           // C/E pixel group b
    const int c2 = ln + 32*ct;        // F: A row (channel)
    const int k2 = ln + 32*kt2;       // F: B row (cluster)

    // ---- prologue: chunk-0 staging loads held RAW (converted in A) ----
    float4 pf[16];
#pragma unroll
    for (int i = 0; i < 16; ++i) {
        int u = (t >> 2) + 128 * i, cQ = u >> 6, nQ = u & 63;
        pf[i] = *(const float4*)(xb + (size_t)(4*cQ + r4) * NN + n_slab + 4*nQ);
    }

    // ---- preload conv_w fragments, ONE k-tile per wave ----
    short8 wfrag[8];
    {
        const float* wr = convw + (size_t)(ln + 32*kt) * CC + 8*q;
#pragma unroll
        for (int cs = 0; cs < 8; ++cs)
            wfrag[cs] = pack8(*(const float4*)(wr + 16*cs), *(const float4*)(wr + 16*cs + 4));
    }

    f32x16 vacc;
#pragma unroll
    for (int i = 0; i < 16; ++i) vacc[i] = 0.f;
    float asacc = 0.f;

#pragma unroll 1
    for (int chk = 0; chk < NCH; ++chk) {
        // ---- A: convert pf -> bf16, write xs[n][c] + xc[c][n] ----
#pragma unroll
        for (int i = 0; i < 16; ++i) {
            int u = (t >> 2) + 128 * i, cQ = u >> 6, nQ = u & 63;
            unsigned d0 = f2bf(pf[i].x) | (f2bf(pf[i].y) << 16);
            unsigned d1 = f2bf(pf[i].z) | (f2bf(pf[i].w) << 16);
            // xc: straight write, 4 consecutive n at row c (512B rows, 32 chunks)
            int c = 4*cQ + r4;
            *(uint2*)((char*)xc + c*512 + ((((nQ >> 1) ^ (c & 31)) << 4) | ((nQ & 1) * 8)))
                = make_uint2(d0, d1);
            // xs: quad 4x4 shuffle transpose (verified round 2), 256B rows
            unsigned q0 = (unsigned)__shfl_xor((int)d0, 1);
            unsigned q1 = (unsigned)__shfl_xor((int)d1, 1);
            unsigned e, f;
            if (r4 & 1) { e = (q0 >> 16) | (d0 & 0xffff0000u);
                          f = (q1 >> 16) | (d1 & 0xffff0000u); }
            else        { e = (d0 & 0xffffu) | (q0 << 16);
                          f = (d1 & 0xffffu) | (q1 << 16); }
            unsigned s2 = (unsigned)__shfl_xor((int)((r4 & 2) ? e : f), 2);
            unsigned w0 = (r4 & 2) ? s2 : e;
            unsigned w1 = (r4 & 2) ? f : s2;
            int nn  = 4*nQ + r4;
            int chp = (cQ >> 1) ^ (nn & 7);
            *(uint2*)((char*)xs + nn*256 + (chp << 4) + (cQ & 1)*8) = make_uint2(w0, w1);
        }
        // ---- B: issue next chunk's staging loads (hidden under C/D/E/F) ----
        if (chk + 1 < NCH) {
            const int gn1 = n_slab + (chk + 1) * PCH;
#pragma unroll
            for (int i = 0; i < 16; ++i) {
                int u = (t >> 2) + 128 * i, cQ = u >> 6, nQ = u & 63;
                pf[i] = *(const float4*)(xb + (size_t)(4*cQ + r4) * NN + gn1 + 4*nQ);
            }
        }
        LDS_FENCE_BARRIER();   // #1: xs, xc visible

        // ---- C: logits, k-tile kt, pixel groups pa/pb (64 px per wave) ----
        f32x16 lacc_a, lacc_b;
#pragma unroll
        for (int i = 0; i < 16; ++i) { lacc_a[i] = 0.f; lacc_b[i] = 0.f; }
#pragma unroll
        for (int cs = 0; cs < 8; ++cs) {
            int chx = (2*cs + q) ^ (ln & 7);   // pa&7 == pb&7 == ln&7
            short8 xfa = *(const short8*)((const char*)xs + pa*256 + (chx << 4));
            short8 xfb = *(const short8*)((const char*)xs + pb*256 + (chx << 4));
            lacc_a = __builtin_amdgcn_mfma_f32_32x32x16_bf16(wfrag[cs], xfa, lacc_a, 0, 0, 0);
            lacc_b = __builtin_amdgcn_mfma_f32_32x32x16_bf16(wfrag[cs], xfb, lacc_b, 0, 0, 0);
        }

        // ---- D: exp + per-k-tile sums; cross-k-tile via redsm (free: bar #2) ----
        float ssa = 0.f, ssb = 0.f;
#pragma unroll
        for (int i = 0; i < 16; ++i) { float e2 = __expf(lacc_a[i]); lacc_a[i] = e2; ssa += e2; }
#pragma unroll
        for (int i = 0; i < 16; ++i) { float e2 = __expf(lacc_b[i]); lacc_b[i] = e2; ssb += e2; }
        ssa += __shfl_xor(ssa, 32);   // q-halves hold complementary k rows of tile kt
        ssb += __shfl_xor(ssb, 32);
        if (q == 0) { redsm[kt][pa] = ssa; redsm[kt][pb] = ssb; }
        LDS_FENCE_BARRIER();   // #2: xs reads done (al aliases xs) + redsm visible

        // ---- E: scale, a -> al[k][n] (512B rows), swizzled scalar b16 writes ----
        float inva = 1.0f / (redsm[0][pa] + redsm[1][pa]);
        float invb = 1.0f / (redsm[0][pb] + redsm[1][pb]);
#pragma unroll
        for (int i = 0; i < 16; ++i) {
            int k_ = 32*kt + 4*q + (i & 3) + 8*(i >> 2);
            *(unsigned short*)((char*)al + k_*512 + ((((pa >> 3) ^ (k_ & 31)) << 4) | ((pa & 7)*2)))
                = (unsigned short)f2bf(lacc_a[i] * inva);
            *(unsigned short*)((char*)al + k_*512 + ((((pb >> 3) ^ (k_ & 31)) << 4) | ((pb & 7)*2)))
                = (unsigned short)f2bf(lacc_b[i] * invb);
        }
        LDS_FENCE_BARRIER();   // #3: al ready

        // ---- F: vlad D[c][k] += X x A^T, wave tile (ct,kt2); all from LDS ----
#pragma unroll
        for (int ns = 0; ns < 16; ++ns) {
            int ca = (2*ns + q) ^ (c2 & 31);
            short8 af = *(const short8*)((const char*)xc + c2*512 + (ca << 4));
            int cb = (2*ns + q) ^ (k2 & 31);
            short8 bf = *(const short8*)((const char*)al + k2*512 + (cb << 4));
            vacc = __builtin_amdgcn_mfma_f32_32x32x16_bf16(af, bf, vacc, 0, 0, 0);
            if (ct == 0) {   // asum: ct>0 waves read identical al rows; one counts
#pragma unroll
                for (int e = 0; e < 8; ++e)
                    asacc += __uint_as_float(((unsigned)(unsigned short)bf[e]) << 16);
            }
        }
        LDS_FENCE_BARRIER();   // #4: al/xc reads done; LDS free for next A
    }

    // ---- epilogue: vlad partial tile -> plain float4 stores (NO atomics) ----
    {
        float* base = (slab == 0)
            ? vlad + (size_t)b * KK * CC
            : wsf + (size_t)(slab - 1) * VSTRIDE + (size_t)b * KK * CC;
        float* vb = base + (size_t)k2 * CC + 32*ct + 4*q;
#pragma unroll
        for (int g = 0; g < 4; ++g) {
            float4 o;
            o.x = vacc[4*g+0]; o.y = vacc[4*g+1]; o.z = vacc[4*g+2]; o.w = vacc[4*g+3];
            *(float4*)(vb + 8*g) = o;   // q0+q1 lanes tile the full 64B lines
        }
    }

    // ---- asum: combine q-halves; ct==0 waves hold k2 = ln + 32*kt2 ----
    if (ct == 0) {
        asacc += __shfl_xor(asacc, 32);
        if (q == 0)
            wsf[3 * VSTRIDE + (size_t)slab * BB * KK + (size_t)b * KK + k2] = asacc;
    }
}

// ---- Phase 2a: per-(b,k) row: sum partials + subtract + intra-normalize ----
// 1024 blocks x 4 waves, one row per wave: fully parallel streaming.
__global__ __launch_bounds__(256) void nv_phase2a(
    float* __restrict__ vlad,        // in: slab-0 partial / out: intra-normalized
    float* __restrict__ wsf,         // partials + asum; ss residuals written here
    const float* __restrict__ cent)  // [K][C]
{
    const int idx  = blockIdx.x * 4 + (threadIdx.x >> 6);   // row 0..4095
    const int b    = idx >> 6, k = idx & 63;
    const int lane = threadIdx.x & 63;
    const float* ap = wsf + 3 * VSTRIDE;                    // [4][B][K]

    float a = ap[0*BB*KK + b*KK + k] + ap[1*BB*KK + b*KK + k]
            + ap[2*BB*KK + b*KK + k] + ap[3*BB*KK + b*KK + k];
    size_t o = ((size_t)b * KK + k) * CC + lane;
    float x0 = vlad[o]      + wsf[o]      + wsf[VSTRIDE + o]      + wsf[2*VSTRIDE + o];
    float x1 = vlad[o + 64] + wsf[o + 64] + wsf[VSTRIDE + o + 64] + wsf[2*VSTRIDE + o + 64];
    x0 -= a * cent[k * CC + lane];
    x1 -= a * cent[k * CC + lane + 64];
    float ss = x0 * x0 + x1 * x1;
#pragma unroll
    for (int m = 1; m < 64; m <<= 1) ss += __shfl_xor(ss, m, 64);
    float rn = 1.0f / fmaxf(sqrtf(ss), 1e-12f);
    vlad[o]      = x0 * rn;
    vlad[o + 64] = x1 * rn;
    if (lane == 0)
        wsf[3 * VSTRIDE + 4*BB*KK + idx] = ss * rn * rn;    // ~1 residual per row
}

// ---- Phase 2b: global L2 scale: g = sum_k ss, out *= 1/sqrt(g) ----
// 512 blocks (8 per b) x 256 threads, 4 floats each.
__global__ __launch_bounds__(256) void nv_phase2b(
    float* __restrict__ vlad,
    const float* __restrict__ wsf)
{
    const int b  = blockIdx.x >> 3, sl = blockIdx.x & 7;
    const int t  = threadIdx.x;
    const float* ssp = wsf + 3 * VSTRIDE + 4*BB*KK;
    float g = ssp[b * KK + (t & 63)];
#pragma unroll
    for (int m = 1; m < 64; m <<= 1) g += __shfl_xor(g, m, 64);
    float gs = 1.0f / fmaxf(sqrtf(g), 1e-12f);
    float4* p = (float4*)(vlad + (size_t)b * KK * CC + sl * 1024 + t * 4);
    float4 w = *p;
    w.x *= gs; w.y *= gs; w.z *= gs; w.w *= gs;
    *p = w;
}

extern "C" void kernel_launch(void* const* d_in, const int* in_sizes, int n_in,
                              void* d_out, int out_size, void* d_ws, size_t ws_size,
                              hipStream_t stream) {
    const float* x     = (const float*)d_in[0];
    const float* convw = (const float*)d_in[1];
    const float* cent  = (const float*)d_in[2];
    float* out = (float*)d_out;
    float* wsf = (float*)d_ws;   // 3*VSTRIDE partials + 4*B*K asum + B*K ss ~ 6.4 MB

    nv_phase1<<<dim3(NSLAB, BB), 512, 0, stream>>>(x, convw, out, wsf);
    nv_phase2a<<<1024, 256, 0, stream>>>(out, wsf, cent);
    nv_phase2b<<<512, 256, 0, stream>>>(out, wsf);
}

// Round 15
// 49.247 us; speedup vs baseline: 1.6594x; 1.5061x over previous
//
#include <hip/hip_runtime.h>
#include <math.h>

#define BB 64
#define CC 128
#define KK 64
#define NN 4096
#define PCH 128            // pixels per chunk (r7-proven)
#define NCH 8              // chunks per block
#define SLAB (PCH*NCH)     // 1024 pixels per block
#define NSLAB (NN/SLAB)    // 4 slabs
#define VSTRIDE ((size_t)BB*KK*CC)   // one vlad partial copy (524288 floats)

typedef __attribute__((ext_vector_type(8))) short short8;
typedef __attribute__((ext_vector_type(16))) float f32x16;

// fp32 -> bf16 bits, round-to-nearest-even
__device__ __forceinline__ unsigned f2bf(float f) {
    unsigned u = __float_as_uint(f);
    return (u + 0x7fffu + ((u >> 16) & 1u)) >> 16;
}

__device__ __forceinline__ short8 pack8(float4 a, float4 b) {
    short8 r;
    r[0]=(short)f2bf(a.x); r[1]=(short)f2bf(a.y); r[2]=(short)f2bf(a.z); r[3]=(short)f2bf(a.w);
    r[4]=(short)f2bf(b.x); r[5]=(short)f2bf(b.y); r[6]=(short)f2bf(b.z); r[7]=(short)f2bf(b.w);
    return r;
}

// LDS-only fence barrier: drains this wave's ds ops for cross-wave visibility
// but leaves global loads (vmcnt) in flight across the barrier (prefetch lives).
#define LDS_FENCE_BARRIER() do {                                  \
    asm volatile("s_waitcnt lgkmcnt(0)" ::: "memory");            \
    __builtin_amdgcn_s_barrier();                                 \
} while (0)

// ---------------- Phase 1: logits -> softmax -> vlad partials (MFMA bf16) ----
// EXACT r7 recipe (48.9us champion: PCH=128, pf[8] raw prefetch, (512,2),
// both MFMA operands from LDS, plain stores) with ONE structural change:
//   - xs/xc double-buffered + al de-aliased (own 16KB) -> barrier #4 removed.
//     3 fences/chunk instead of 4; waves flow F -> A/B with no lockstep wait,
//     so staging writes/loads overlap sibling waves' MFMAs.
//   Hazard audit: every wave executes lgkmcnt(0) before bar#1(i+1), draining
//   its F(i) ds_reads -> E(i+1) al writes and A(i+2) same-buffer writes are
//   barrier-ordered. redsm WAR likewise separated by bar#1.
// LDS: 2x32(xs) + 2x32(xc) + 16(al) + 1(redsm) = 145KB, 1 block/CU.
// Register ledger: pf[8]=32 + wfrag=16 + 32 AGPR + temps ~= 90 << 256. The
// r8-style fragment-sum asum replaces r7's asum_l[16]+butterfly (-16 regs).
__global__ __launch_bounds__(512, 2) void nv_phase1(
    const float* __restrict__ x,      // [B][C][N]
    const float* __restrict__ convw,  // [K][C]
    float* __restrict__ vlad,         // [B][K][C]  slab-0 partial (d_out)
    float* __restrict__ wsf)          // slabs 1..3 vlad partials + asum + ss
{
    __shared__ alignas(16) unsigned short xs[2][PCH*CC];  // 2x32 KB, [n][c], swizzled
    __shared__ alignas(16) unsigned short xc[2][CC*PCH];  // 2x32 KB, [c][n], swizzled
    __shared__ alignas(16) unsigned short al[KK*PCH];     // 16 KB a[k][n] (no aliasing)
    __shared__ float redsm[2][PCH];                       // softmax denom cross-wave

    const int t  = threadIdx.x;
    const int b  = blockIdx.y;
    const int slab = blockIdx.x;
    const int n_slab = slab * SLAB;
    const int l   = t & 63;
    const int wid = t >> 6;           // wave 0..7
    const int ln  = l & 31;
    const int q   = l >> 5;
    const int r4  = t & 3;
    const int kt  = wid & 1;          // C: k-tile
    const int nt  = wid >> 1;         // C: n-tile
    const int ct  = wid & 3;          // F: c-tile
    const int kt2 = wid >> 2;         // F: k-tile

    const float* xb = x + (size_t)b * CC * NN;
    const int n_ = ln + 32*nt;        // C/D/E pixel (chunk-local)
    const int c2 = ln + 32*ct;        // F: A row (channel)
    const int k2 = ln + 32*kt2;       // F: B row (cluster)

    // ---- prologue: chunk-0 staging loads held RAW (converted in A) ----
    float4 pf[8];
#pragma unroll
    for (int i = 0; i < 8; ++i) {
        int u = (t >> 2) + 128 * i, cQ = u >> 5, nQ = u & 31;
        pf[i] = *(const float4*)(xb + (size_t)(4*cQ + r4) * NN + n_slab + 4*nQ);
    }

    // ---- preload conv_w fragments (A of logits), reused for all chunks ----
    short8 wfrag[8];
    {
        const float* wr = convw + (size_t)(ln + 32*kt) * CC + 8*q;
#pragma unroll
        for (int cs = 0; cs < 8; ++cs)
            wfrag[cs] = pack8(*(const float4*)(wr + 16*cs), *(const float4*)(wr + 16*cs + 4));
    }

    f32x16 vacc;
#pragma unroll
    for (int i = 0; i < 16; ++i) vacc[i] = 0.f;
    float asacc = 0.f;

#pragma unroll 1
    for (int chk = 0; chk < NCH; ++chk) {
        unsigned short* xsp = xs[chk & 1];
        unsigned short* xcp = xc[chk & 1];
        // ---- A: convert pf -> bf16, write xs[p][n][c] + xc[p][c][n] ----
#pragma unroll
        for (int i = 0; i < 8; ++i) {
            int u = (t >> 2) + 128 * i, cQ = u >> 5, nQ = u & 31;
            unsigned d0 = f2bf(pf[i].x) | (f2bf(pf[i].y) << 16);
            unsigned d1 = f2bf(pf[i].z) | (f2bf(pf[i].w) << 16);
            // xc: straight write, 4 consecutive n at row c
            int c = 4*cQ + r4;
            *(uint2*)((char*)xcp + c*256 + ((((nQ >> 1) ^ (c & 7)) << 4) | ((nQ & 1) * 8)))
                = make_uint2(d0, d1);
            // xs: quad 4x4 shuffle transpose (verified round 2)
            unsigned q0 = (unsigned)__shfl_xor((int)d0, 1);
            unsigned q1 = (unsigned)__shfl_xor((int)d1, 1);
            unsigned e, f;
            if (r4 & 1) { e = (q0 >> 16) | (d0 & 0xffff0000u);
                          f = (q1 >> 16) | (d1 & 0xffff0000u); }
            else        { e = (d0 & 0xffffu) | (q0 << 16);
                          f = (d1 & 0xffffu) | (q1 << 16); }
            unsigned s2 = (unsigned)__shfl_xor((int)((r4 & 2) ? e : f), 2);
            unsigned w0 = (r4 & 2) ? s2 : e;
            unsigned w1 = (r4 & 2) ? f : s2;
            int nn  = 4*nQ + r4;
            int chp = (cQ >> 1) ^ (nn & 7);
            *(uint2*)((char*)xsp + nn*256 + (chp << 4) + (cQ & 1)*8) = make_uint2(w0, w1);
        }
        // ---- B: issue next chunk's staging loads (hidden under C/D/E/F) ----
        if (chk + 1 < NCH) {
            const int gn1 = n_slab + (chk + 1) * PCH;
#pragma unroll
            for (int i = 0; i < 8; ++i) {
                int u = (t >> 2) + 128 * i, cQ = u >> 5, nQ = u & 31;
                pf[i] = *(const float4*)(xb + (size_t)(4*cQ + r4) * NN + gn1 + 4*nQ);
            }
        }
        LDS_FENCE_BARRIER();   // #1: xs[p], xc[p] visible (also orders al/redsm WARs)

        // ---- C: logits D[k][n] = W x X, wave tile (kt, nt) ----
        f32x16 lacc;
#pragma unroll
        for (int i = 0; i < 16; ++i) lacc[i] = 0.f;
#pragma unroll
        for (int cs = 0; cs < 8; ++cs) {
            int chx = (2*cs + q) ^ (n_ & 7);
            short8 xf = *(const short8*)((const char*)xsp + n_*256 + (chx << 4));
            lacc = __builtin_amdgcn_mfma_f32_32x32x16_bf16(wfrag[cs], xf, lacc, 0, 0, 0);
        }

        // ---- D: softmax over k, no max-sub (|logit| <~ 8, exp safe in fp32) ----
        float ssum = 0.f;
#pragma unroll
        for (int i = 0; i < 16; ++i) { float e2 = __expf(lacc[i]); lacc[i] = e2; ssum += e2; }
        ssum += __shfl_xor(ssum, 32);
        if (q == 0) redsm[kt][n_] = ssum;
        LDS_FENCE_BARRIER();   // #2: denom visible

        // ---- E: scale, a -> al[k][n], swizzled scalar b16 writes ----
        float inv = 1.0f / (redsm[0][n_] + redsm[1][n_]);
#pragma unroll
        for (int i = 0; i < 16; ++i) {
            float a = lacc[i] * inv;
            int k_ = 32*kt + 4*q + (i & 3) + 8*(i >> 2);
            al[k_*128 + ((((n_ >> 3) ^ (k_ & 7)) << 3) | (n_ & 7))] = (unsigned short)f2bf(a);
        }
        LDS_FENCE_BARRIER();   // #3: al ready

        // ---- F: vlad D[c][k] += X x A^T, wave tile (ct,kt2); all from LDS ----
#pragma unroll
        for (int ns = 0; ns < 8; ++ns) {
            int ca = (2*ns + q) ^ (c2 & 7);
            short8 af = *(const short8*)((const char*)xcp + c2*256 + (ca << 4));
            int cb = (2*ns + q) ^ (k2 & 7);
            short8 bf = *(const short8*)((const char*)al + k2*256 + (cb << 4));
            vacc = __builtin_amdgcn_mfma_f32_32x32x16_bf16(af, bf, vacc, 0, 0, 0);
            if (ct == 0) {   // asum: ct>0 waves read identical al rows; one counts
#pragma unroll
                for (int e = 0; e < 8; ++e)
                    asacc += __uint_as_float(((unsigned)(unsigned short)bf[e]) << 16);
            }
        }
        // no barrier #4: next A writes the OTHER xs/xc buffer; al/redsm writes
        // of iteration i+1 are ordered behind bar#1/#2 (hazard audit above).
    }

    // ---- epilogue: vlad partial tile -> plain float4 stores (NO atomics) ----
    {
        float* base = (slab == 0)
            ? vlad + (size_t)b * KK * CC
            : wsf + (size_t)(slab - 1) * VSTRIDE + (size_t)b * KK * CC;
        float* vb = base + (size_t)k2 * CC + 32*ct + 4*q;
#pragma unroll
        for (int g = 0; g < 4; ++g) {
            float4 o;
            o.x = vacc[4*g+0]; o.y = vacc[4*g+1]; o.z = vacc[4*g+2]; o.w = vacc[4*g+3];
            *(float4*)(vb + 8*g) = o;   // q0+q1 lanes tile the full 64B lines
        }
    }

    // ---- asum: combine q-halves; ct==0 waves hold k2 = ln + 32*kt2 ----
    if (ct == 0) {
        asacc += __shfl_xor(asacc, 32);
        if (q == 0)
            wsf[3 * VSTRIDE + (size_t)slab * BB * KK + (size_t)b * KK + k2] = asacc;
    }
}

// ---- Phase 2a: per-(b,k) row: sum partials + subtract + intra-normalize ----
// 1024 blocks x 4 waves, one row per wave: fully parallel streaming (r14-verified).
__global__ __launch_bounds__(256) void nv_phase2a(
    float* __restrict__ vlad,        // in: slab-0 partial / out: intra-normalized
    float* __restrict__ wsf,         // partials + asum; ss residuals written here
    const float* __restrict__ cent)  // [K][C]
{
    const int idx  = blockIdx.x * 4 + (threadIdx.x >> 6);   // row 0..4095
    const int b    = idx >> 6, k = idx & 63;
    const int lane = threadIdx.x & 63;
    const float* ap = wsf + 3 * VSTRIDE;                    // [4][B][K]

    float a = ap[0*BB*KK + b*KK + k] + ap[1*BB*KK + b*KK + k]
            + ap[2*BB*KK + b*KK + k] + ap[3*BB*KK + b*KK + k];
    size_t o = ((size_t)b * KK + k) * CC + lane;
    float x0 = vlad[o]      + wsf[o]      + wsf[VSTRIDE + o]      + wsf[2*VSTRIDE + o];
    float x1 = vlad[o + 64] + wsf[o + 64] + wsf[VSTRIDE + o + 64] + wsf[2*VSTRIDE + o + 64];
    x0 -= a * cent[k * CC + lane];
    x1 -= a * cent[k * CC + lane + 64];
    float ss = x0 * x0 + x1 * x1;
#pragma unroll
    for (int m = 1; m < 64; m <<= 1) ss += __shfl_xor(ss, m, 64);
    float rn = 1.0f / fmaxf(sqrtf(ss), 1e-12f);
    vlad[o]      = x0 * rn;
    vlad[o + 64] = x1 * rn;
    if (lane == 0)
        wsf[3 * VSTRIDE + 4*BB*KK + idx] = ss * rn * rn;    // row residual
}

// ---- Phase 2b: global L2 scale: g = sum_k ss, out *= 1/sqrt(g) ----
__global__ __launch_bounds__(256) void nv_phase2b(
    float* __restrict__ vlad,
    const float* __restrict__ wsf)
{
    const int b  = blockIdx.x >> 3, sl = blockIdx.x & 7;
    const int t  = threadIdx.x;
    const float* ssp = wsf + 3 * VSTRIDE + 4*BB*KK;
    float g = ssp[b * KK + (t & 63)];
#pragma unroll
    for (int m = 1; m < 64; m <<= 1) g += __shfl_xor(g, m, 64);
    float gs = 1.0f / fmaxf(sqrtf(g), 1e-12f);
    float4* p = (float4*)(vlad + (size_t)b * KK * CC + sl * 1024 + t * 4);
    float4 w = *p;
    w.x *= gs; w.y *= gs; w.z *= gs; w.w *= gs;
    *p = w;
}

extern "C" void kernel_launch(void* const* d_in, const int* in_sizes, int n_in,
                              void* d_out, int out_size, void* d_ws, size_t ws_size,
                              hipStream_t stream) {
    const float* x     = (const float*)d_in[0];
    const float* convw = (const float*)d_in[1];
    const float* cent  = (const float*)d_in[2];
    float* out = (float*)d_out;
    float* wsf = (float*)d_ws;   // 3*VSTRIDE partials + 4*B*K asum + B*K ss ~ 6.4 MB

    nv_phase1<<<dim3(NSLAB, BB), 512, 0, stream>>>(x, convw, out, wsf);
    nv_phase2a<<<1024, 256, 0, stream>>>(out, wsf, cent);
    nv_phase2b<<<512, 256, 0, stream>>>(out, wsf);
}